// Round 16
// baseline (1061.200 us; speedup 1.0000x reference)
//
#include <hip/hip_runtime.h>
#include <hip/hip_bf16.h>

typedef __attribute__((ext_vector_type(8))) short bf16x8;
typedef __attribute__((ext_vector_type(4))) float f32x4;
typedef unsigned short u16;
typedef __attribute__((ext_vector_type(4))) unsigned short u16x4;

#define L_ 4
#define E_ 1024
#define H_ 16
#define F_ 4096
#define B_ 8
#define S_ 512
#define T_ 4096
#define GEN_N 1200
#define GEN_PAD 1280

#define AS1 __attribute__((address_space(1)))
#define AS3 __attribute__((address_space(3)))

static __device__ __forceinline__ u16 f2bf(float f) {
  unsigned u = __float_as_uint(f);
  unsigned r = (u + 0x7fffu + ((u >> 16) & 1u)) >> 16;
  return (u16)r;
}

static __device__ __forceinline__ unsigned cvt_pk_bf16(float lo, float hi) {
  unsigned r;
  asm("v_cvt_pk_bf16_f32 %0, %1, %2" : "=v"(r) : "v"(lo), "v"(hi));
  return r;
}

static __device__ __forceinline__ float fast_gelu(float v) {
  float y = 0.7978845608f * (v + 0.044715f * v * v * v);
  y = fminf(fmaxf(y, -9.f), 9.f);
  float e2 = __expf(2.f * y);
  float th = (e2 - 1.f) / (e2 + 1.f);
  return 0.5f * v * (1.f + th);
}

// ---------------- f32 -> bf16 convert (single buffer) ----------------
__global__ __launch_bounds__(256) void cvt_bf16(const float* __restrict__ src,
                                                u16* __restrict__ dst, int n) {
  int i = (blockIdx.x * 256 + threadIdx.x) * 4;
  if (i >= n) return;
  float4 v = *reinterpret_cast<const float4*>(src + i);
  u16x4 o = {f2bf(v.x), f2bf(v.y), f2bf(v.z), f2bf(v.w)};
  *reinterpret_cast<u16x4*>(dst + i) = o;
}

// ---------------- merged per-layer weight convert (4 segments) ----------------
__global__ __launch_bounds__(256) void cvt4_k(const float* __restrict__ s0,
                                              const float* __restrict__ s1,
                                              const float* __restrict__ s2,
                                              const float* __restrict__ s3,
                                              u16* __restrict__ d0, u16* __restrict__ d1,
                                              u16* __restrict__ d2, u16* __restrict__ d3) {
  int q = blockIdx.x * 256 + threadIdx.x;
  const float* s;
  u16* d;
  int i;
  if (q < 786432) { s = s0; d = d0; i = q; }
  else if (q < 786432 + 262144) { s = s1; d = d1; i = q - 786432; }
  else if (q < 786432 + 262144 + 1048576) { s = s2; d = d2; i = q - (786432 + 262144); }
  else { s = s3; d = d3; i = q - (786432 + 262144 + 1048576); }
  i *= 4;
  float4 v = *reinterpret_cast<const float4*>(s + i);
  u16x4 o = {f2bf(v.x), f2bf(v.y), f2bf(v.z), f2bf(v.w)};
  *reinterpret_cast<u16x4*>(d + i) = o;
}

// ---------------- dist -> u8 with pad sentinel (once per call) ----------------
// d8g[(b*S+q)*S + k] = pad(b,k) ? 200 : dist[b][q][k]
__global__ __launch_bounds__(256) void d8pre_k(const int* __restrict__ dist,
                                               const int* __restrict__ vseq,
                                               unsigned char* __restrict__ d8g) {
  int idx = blockIdx.x * 256 + threadIdx.x;   // quad index over B*S*S/4
  int k4 = idx & 127;
  int b = idx >> 16;
  int4 dv = *reinterpret_cast<const int4*>(dist + (size_t)idx * 4);
  int4 vv = *reinterpret_cast<const int4*>(vseq + b * S_ + k4 * 4);
  uchar4 o;
  o.x = (vv.x == 0) ? (unsigned char)200 : (unsigned char)dv.x;
  o.y = (vv.y == 0) ? (unsigned char)200 : (unsigned char)dv.y;
  o.z = (vv.z == 0) ? (unsigned char)200 : (unsigned char)dv.z;
  o.w = (vv.w == 0) ? (unsigned char)200 : (unsigned char)dv.w;
  *reinterpret_cast<uchar4*>(d8g + (size_t)idx * 4) = o;
}

// ---------------- embedding ----------------
__global__ __launch_bounds__(256) void embed_k(const float* __restrict__ val_emb,
                                               const float* __restrict__ ring_emb,
                                               const int* __restrict__ vseq,
                                               const int* __restrict__ rseq,
                                               float* __restrict__ h, u16* __restrict__ xbf) {
  int tok = blockIdx.x;
  int e = threadIdx.x * 4;
  int v = vseq[tok], r = rseq[tok];
  float4 a = *reinterpret_cast<const float4*>(val_emb + v * E_ + e);
  float4 b = *reinterpret_cast<const float4*>(ring_emb + r * E_ + e);
  float4 o;
  o.x = (a.x + b.x) * 32.f; o.y = (a.y + b.y) * 32.f;
  o.z = (a.z + b.z) * 32.f; o.w = (a.w + b.w) * 32.f;
  *reinterpret_cast<float4*>(h + (size_t)tok * E_ + e) = o;
  u16x4 ob = {f2bf(o.x), f2bf(o.y), f2bf(o.z), f2bf(o.w)};
  *reinterpret_cast<u16x4*>(xbf + (size_t)tok * E_ + e) = ob;
}

// ---------------- LayerNorm: wave-per-token, 4 tokens/block -----------------
__global__ __launch_bounds__(256) void ln_k(const float* hin, const float* add0,
                                            const float* add1, const float* cbias,
                                            const float* g, const float* bta,
                                            float* hout, u16* xout) {
  int tok = blockIdx.x * 4 + (threadIdx.x >> 6);
  int lane = threadIdx.x & 63;
  const float* hp = hin + (size_t)tok * E_;
  float4 v[4];
  #pragma unroll
  for (int p = 0; p < 4; ++p) {
    int e = p * 256 + lane * 4;
    v[p] = *reinterpret_cast<const float4*>(hp + e);
    if (add0) {
      float4 a0 = *reinterpret_cast<const float4*>(add0 + (size_t)tok * E_ + e);
      float4 a1 = *reinterpret_cast<const float4*>(add1 + (size_t)tok * E_ + e);
      float4 cb = *reinterpret_cast<const float4*>(cbias + e);
      v[p].x += a0.x + a1.x + cb.x; v[p].y += a0.y + a1.y + cb.y;
      v[p].z += a0.z + a1.z + cb.z; v[p].w += a0.w + a1.w + cb.w;
    }
  }
  float s = 0.f, q = 0.f;
  #pragma unroll
  for (int p = 0; p < 4; ++p) {
    s += v[p].x + v[p].y + v[p].z + v[p].w;
    q += v[p].x * v[p].x + v[p].y * v[p].y + v[p].z * v[p].z + v[p].w * v[p].w;
  }
  #pragma unroll
  for (int off = 1; off < 64; off <<= 1) {
    s += __shfl_xor(s, off, 64);
    q += __shfl_xor(q, off, 64);
  }
  float mean = s * (1.f / E_);
  float var = q * (1.f / E_) - mean * mean;
  float inv = rsqrtf(var + 1e-5f);
  #pragma unroll
  for (int p = 0; p < 4; ++p) {
    int e = p * 256 + lane * 4;
    float4 gg = *reinterpret_cast<const float4*>(g + e);
    float4 bb = *reinterpret_cast<const float4*>(bta + e);
    float4 o;
    o.x = (v[p].x - mean) * inv * gg.x + bb.x;
    o.y = (v[p].y - mean) * inv * gg.y + bb.y;
    o.z = (v[p].z - mean) * inv * gg.z + bb.z;
    o.w = (v[p].w - mean) * inv * gg.w + bb.w;
    if (hout) *reinterpret_cast<float4*>(hout + (size_t)tok * E_ + e) = o;
    u16x4 ob = {f2bf(o.x), f2bf(o.y), f2bf(o.z), f2bf(o.w)};
    *reinterpret_cast<u16x4*>(xout + (size_t)tok * E_ + e) = ob;
  }
}

// ---------------- gemm_small: 128x256 tile, BK=32, 48KB LDS, 2 blocks/CU -------
// EPI: 0 = bf16+bias (+Vt scatter), 1 = gelu bf16+bias
template <int EPI>
__global__ __launch_bounds__(256, 2) void gemm_small(const u16* __restrict__ A,
                                                     const u16* __restrict__ W,
                                                     const float* __restrict__ bias,
                                                     void* __restrict__ Cp,
                                                     u16* __restrict__ Vt,
                                                     int M, int N, int K, int tilesN) {
  __shared__ __align__(16) char lds[49152];
  int tid = threadIdx.x;
  int wid = tid >> 6, l = tid & 63;
  int wm = wid >> 1, wn = wid & 1;
  int lr = l & 15, lk = l >> 4;
  int nwg = gridDim.x, bid = blockIdx.x;
  int swz = ((nwg & 7) == 0) ? ((bid & 7) * (nwg >> 3) + (bid >> 3)) : bid;
  int tm = swz / tilesN, tn = swz % tilesN;
  int row0 = tm * 128, col0 = tn * 256;

  int srow = tid >> 2;
  int sch = ((tid & 3) ^ ((srow >> 1) & 3)) * 8;
  const u16* gA = A + (size_t)(row0 + srow) * K + sch;
  const u16* gB = W + (size_t)(col0 + srow) * K + sch;
  int wslot = wid * 1024;

  auto stage = [&](int buf, int kt) {
    size_t ko = (size_t)kt * 32;
    int base = buf * 24576;
    #pragma unroll
    for (int i = 0; i < 2; ++i)
      __builtin_amdgcn_global_load_lds((const AS1 void*)(gA + (size_t)i * 64 * K + ko),
                                       (AS3 void*)(lds + base + i * 4096 + wslot), 16, 0, 0);
    #pragma unroll
    for (int i = 0; i < 4; ++i)
      __builtin_amdgcn_global_load_lds((const AS1 void*)(gB + (size_t)i * 64 * K + ko),
                                       (AS3 void*)(lds + base + 8192 + i * 4096 + wslot), 16, 0, 0);
  };

  int ck = (lk ^ ((lr >> 1) & 3)) * 16;
  f32x4 acc[4][8];
  f32x4 z = {0.f, 0.f, 0.f, 0.f};
  #pragma unroll
  for (int m = 0; m < 4; ++m)
    #pragma unroll
    for (int n = 0; n < 8; ++n) acc[m][n] = z;

  auto compute = [&](int buf) {
    int base = buf * 24576;
    bf16x8 bfr[8];
    #pragma unroll
    for (int n = 0; n < 8; ++n)
      bfr[n] = *reinterpret_cast<const bf16x8*>(lds + base + 8192 + (wn * 128 + n * 16 + lr) * 64 + ck);
    #pragma unroll
    for (int m = 0; m < 4; ++m) {
      bf16x8 af = *reinterpret_cast<const bf16x8*>(lds + base + (wm * 64 + m * 16 + lr) * 64 + ck);
      #pragma unroll
      for (int n = 0; n < 8; ++n)
        acc[m][n] = __builtin_amdgcn_mfma_f32_16x16x32_bf16(af, bfr[n], acc[m][n], 0, 0, 0);
    }
  };

  int nt = K >> 5;
  stage(0, 0);
  int cur = 0;
  for (int t = 0; t < nt; ++t) {
    if (t + 1 < nt) {
      stage(cur ^ 1, t + 1);
      asm volatile("s_waitcnt vmcnt(6)" ::: "memory");
    } else {
      asm volatile("s_waitcnt vmcnt(0)" ::: "memory");
    }
    __builtin_amdgcn_s_barrier();
    asm volatile("" ::: "memory");
    compute(cur);
    asm volatile("" ::: "memory");
    __builtin_amdgcn_s_barrier();
    cur ^= 1;
  }

  #pragma unroll
  for (int n = 0; n < 8; ++n) {
    int col = col0 + wn * 128 + n * 16 + lr;
    float bv = bias[col];
    #pragma unroll
    for (int m = 0; m < 4; ++m) {
      int rbase = row0 + wm * 64 + m * 16 + lk * 4;
      #pragma unroll
      for (int r2 = 0; r2 < 4; ++r2) {
        float v = acc[m][n][r2] + bv;
        if (EPI == 1) v = fast_gelu(v);
        int row = rbase + r2;
        u16 bw = f2bf(v);
        ((u16*)Cp)[(size_t)row * N + col] = bw;
        if (EPI == 0 && Vt != nullptr && col >= 2 * E_) {
          int dg = col - 2 * E_;
          int hh = dg >> 6, dd = dg & 63;
          int bb = row >> 9, ss = row & 511;
          Vt[((size_t)((bb * 16 + hh) * 64 + dd) << 9) + ss] = bw;
        }
      }
    }
  }
}

// ---------------- big-tile GEMM (2-phase, Wo / W2 / gen) ----------------
// EPI: 2 = raw f32 partial (split-K), 3 = f32+bias
template <int EPI, int NW, int SPLITK>
__global__ __launch_bounds__(512, 2) void gemm_big(const u16* __restrict__ A,
                                                   const u16* __restrict__ W,
                                                   const float* __restrict__ bias,
                                                   void* __restrict__ Cp,
                                                   int M, int N, int K, int tilesN) {
  constexpr int BN = 64 * NW;
  __shared__ __align__(16) u16 As[2][256 * 64];
  __shared__ __align__(16) u16 Bs[2][BN * 64];
  int tid = threadIdx.x;
  int wid = tid >> 6, ln = tid & 63;
  int wm = wid >> 2, wn = wid & 3;
  int lr = ln & 15, lk = ln >> 4;
  int nwg = gridDim.x;
  int bid = blockIdx.x;
  int swz = ((nwg & 7) == 0) ? ((bid & 7) * (nwg >> 3) + (bid >> 3)) : bid;
  int sp = 0, tile = swz;
  if (SPLITK > 1) { sp = swz & (SPLITK - 1); tile = swz / SPLITK; }
  int tm = tile / tilesN, tn = tile % tilesN;
  int row0 = tm * 256, col0 = tn * BN;
  int Ks = K / SPLITK;
  int kbase = sp * Ks;

  int srow = tid >> 3;
  int schunk = ((tid & 7) ^ (srow & 7)) * 8;
  const u16* gA = A + (size_t)(row0 + srow) * K + kbase + schunk;
  const u16* gB = W + (size_t)(col0 + srow) * K + kbase + schunk;
  size_t ldsBase = (size_t)((wid << 3) * 64) * 2;

  auto stage = [&](int buf, int kt) {
    size_t ko = (size_t)kt * 64;
    #pragma unroll
    for (int i = 0; i < 4; ++i)
      __builtin_amdgcn_global_load_lds(
          (const AS1 void*)(gA + (size_t)i * 64 * K + ko),
          (AS3 void*)((char*)&As[buf][0] + ldsBase + (size_t)i * 64 * 128), 16, 0, 0);
    #pragma unroll
    for (int i = 0; i < NW; ++i)
      __builtin_amdgcn_global_load_lds(
          (const AS1 void*)(gB + (size_t)i * 64 * K + ko),
          (AS3 void*)((char*)&Bs[buf][0] + ldsBase + (size_t)i * 64 * 128), 16, 0, 0);
  };

  f32x4 acc[8][NW];
  f32x4 z = {0.f, 0.f, 0.f, 0.f};
  #pragma unroll
  for (int m = 0; m < 8; ++m)
    #pragma unroll
    for (int n = 0; n < NW; ++n) acc[m][n] = z;

  auto compute = [&](int buf) {
    #pragma unroll
    for (int s = 0; s < 2; ++s) {
      int ch = ((s * 4 + lk) ^ (lr & 7)) * 8;
      bf16x8 bfr[NW];
      #pragma unroll
      for (int n = 0; n < NW; ++n)
        bfr[n] = *reinterpret_cast<const bf16x8*>(&Bs[buf][(wn * (16 * NW) + n * 16 + lr) * 64 + ch]);
      #pragma unroll
      for (int m = 0; m < 8; ++m) {
        bf16x8 af = *reinterpret_cast<const bf16x8*>(&As[buf][(wm * 128 + m * 16 + lr) * 64 + ch]);
        #pragma unroll
        for (int n = 0; n < NW; ++n)
          acc[m][n] = __builtin_amdgcn_mfma_f32_16x16x32_bf16(af, bfr[n], acc[m][n], 0, 0, 0);
      }
    }
  };

  int nt = Ks >> 6;
  stage(0, 0);
  int cur = 0;
  for (int t = 0; t < nt; ++t) {
    if (t + 1 < nt) {
      stage(cur ^ 1, t + 1);
      if constexpr (NW == 2) asm volatile("s_waitcnt vmcnt(6)" ::: "memory");
      else if constexpr (NW == 3) asm volatile("s_waitcnt vmcnt(7)" ::: "memory");
      else asm volatile("s_waitcnt vmcnt(8)" ::: "memory");
    } else {
      asm volatile("s_waitcnt vmcnt(0)" ::: "memory");
    }
    __builtin_amdgcn_s_barrier();
    asm volatile("" ::: "memory");
    compute(cur);
    asm volatile("" ::: "memory");
    __builtin_amdgcn_s_barrier();
    cur ^= 1;
  }

  #pragma unroll
  for (int n = 0; n < NW; ++n) {
    int col = col0 + wn * (16 * NW) + n * 16 + lr;
    if (col >= N) continue;
    float bv = (EPI == 2) ? 0.f : bias[col];
    #pragma unroll
    for (int m = 0; m < 8; ++m) {
      int rbase = row0 + wm * 128 + m * 16 + lk * 4;
      #pragma unroll
      for (int r2 = 0; r2 < 4; ++r2) {
        float v = acc[m][n][r2] + bv;
        int row = rbase + r2;
        if (EPI == 2)
          ((float*)Cp)[(size_t)sp * M * N + (size_t)row * N + col] = v;
        else
          ((float*)Cp)[(size_t)row * N + col] = v;
      }
    }
  }
}

// ---------------- fused attention, high-occupancy (8 blocks/CU) ----------------
// No LDS dist staging: gathers precomputed u8 d8g (L2/L3 resident) as u32.
__global__ __launch_bounds__(256, 8) void attn_fused_k(const u16* __restrict__ qkv,
                                                       const unsigned char* __restrict__ d8g,
                                                       const float* __restrict__ dist_emb,
                                                       const u16* __restrict__ Vt,
                                                       u16* __restrict__ ctx) {
  int blk = blockIdx.x;
  int bh = blk & 127;
  int qt = blk >> 7;
  int b = bh >> 4, h = bh & 15;
  int tid = threadIdx.x, wv = tid >> 6, l = tid & 63;
  int lr = l & 15, lk = l >> 4;

  __shared__ float de[208];
  for (int i = tid; i < 208; i += 256)
    de[i] = (i < 200) ? dist_emb[i * H_ + h] : -1e30f;
  __syncthreads();

  int q0 = qt * 64 + wv * 16;
  int nv = 4 * qt + wv + 1;
  int qglob = q0 + lr;
  const unsigned char* drow = d8g + ((size_t)(b * S_ + qglob) << 9);

  bf16x8 aq0 = *reinterpret_cast<const bf16x8*>(
      qkv + (size_t)(b * S_ + q0 + lr) * 3072 + h * 64 + lk * 8);
  bf16x8 aq1 = *reinterpret_cast<const bf16x8*>(
      qkv + (size_t)(b * S_ + q0 + lr) * 3072 + h * 64 + 32 + lk * 8);

  float sm = 0.f;
  f32x4 z = {0.f, 0.f, 0.f, 0.f};
  f32x4 acc_o[4] = {z, z, z, z};

  int sA = lr + ((2 * lk) & 3) * 16;
  int sB = lr + ((2 * lk + 1) & 3) * 16;
  int jsel = (lk >= 2);

  const u16* kBase = qkv + (size_t)(b * S_ + lr) * 3072 + E_ + h * 64 + lk * 8;
  const u16* vBase = Vt + (size_t)(bh * 64 + lr) * S_ + lk * 8;

  int ngroups = (nv + 1) >> 1;
  #pragma unroll 1
  for (int g = 0; g < ngroups; ++g) {
    // ---- QK^T (swapped) ----
    f32x4 s0 = z, s1 = z;
    {
      const u16* kb = kBase + (size_t)(2 * g) * 16 * 3072;
      bf16x8 bk0 = *reinterpret_cast<const bf16x8*>(kb);
      bf16x8 bk1 = *reinterpret_cast<const bf16x8*>(kb + 32);
      s0 = __builtin_amdgcn_mfma_f32_16x16x32_bf16(bk0, aq0, s0, 0, 0, 0);
      s0 = __builtin_amdgcn_mfma_f32_16x16x32_bf16(bk1, aq1, s0, 0, 0, 0);
    }
    if (2 * g + 1 < nv) {
      const u16* kb = kBase + (size_t)(2 * g + 1) * 16 * 3072;
      bf16x8 bk0 = *reinterpret_cast<const bf16x8*>(kb);
      bf16x8 bk1 = *reinterpret_cast<const bf16x8*>(kb + 32);
      s1 = __builtin_amdgcn_mfma_f32_16x16x32_bf16(bk0, aq0, s1, 0, 0, 0);
      s1 = __builtin_amdgcn_mfma_f32_16x16x32_bf16(bk1, aq1, s1, 0, 0, 0);
    }
    // ---- bias + causal + exp (u32 dist gather) ----
    float e0[4], e1[4];
    {
      unsigned dd = *reinterpret_cast<const unsigned*>(drow + (2 * g) * 16 + lk * 4);
      #pragma unroll
      for (int r2 = 0; r2 < 4; ++r2) {
        int kg = (2 * g) * 16 + lk * 4 + r2;
        float e = 0.f;
        if (kg <= qglob)
          e = __expf(s0[r2] * 0.125f + de[(dd >> (8 * r2)) & 255]);
        e0[r2] = e; sm += e;
      }
    }
    {
      unsigned dd = *reinterpret_cast<const unsigned*>(drow + (2 * g + 1) * 16 + lk * 4);
      #pragma unroll
      for (int r2 = 0; r2 < 4; ++r2) {
        int kg = (2 * g + 1) * 16 + lk * 4 + r2;
        float e = 0.f;
        if (2 * g + 1 < nv && kg <= qglob)
          e = __expf(s1[r2] * 0.125f + de[(dd >> (8 * r2)) & 255]);
        e1[r2] = e; sm += e;
      }
    }
    // ---- pack + shuffle into PV B-frag ----
    unsigned t0p0 = cvt_pk_bf16(e0[0], e0[1]);
    unsigned t0p1 = cvt_pk_bf16(e0[2], e0[3]);
    unsigned t1p0 = cvt_pk_bf16(e1[0], e1[1]);
    unsigned t1p1 = cvt_pk_bf16(e1[2], e1[3]);
    unsigned a00 = __shfl((int)t0p0, sA, 64), a10 = __shfl((int)t1p0, sA, 64);
    unsigned a01 = __shfl((int)t0p1, sA, 64), a11 = __shfl((int)t1p1, sA, 64);
    unsigned b00 = __shfl((int)t0p0, sB, 64), b10 = __shfl((int)t1p0, sB, 64);
    unsigned b01 = __shfl((int)t0p1, sB, 64), b11 = __shfl((int)t1p1, sB, 64);
    unsigned w0 = jsel ? a10 : a00;
    unsigned w1 = jsel ? a11 : a01;
    unsigned w2 = jsel ? b10 : b00;
    unsigned w3 = jsel ? b11 : b01;
    bf16x8 pfrag;
    {
      unsigned pw[4] = {w0, w1, w2, w3};
      pfrag = *reinterpret_cast<bf16x8*>(pw);
    }
    // ---- PV ----
    const u16* vb = vBase + g * 32;
    acc_o[0] = __builtin_amdgcn_mfma_f32_16x16x32_bf16(
        *reinterpret_cast<const bf16x8*>(vb), pfrag, acc_o[0], 0, 0, 0);
    acc_o[1] = __builtin_amdgcn_mfma_f32_16x16x32_bf16(
        *reinterpret_cast<const bf16x8*>(vb + 16 * S_), pfrag, acc_o[1], 0, 0, 0);
    acc_o[2] = __builtin_amdgcn_mfma_f32_16x16x32_bf16(
        *reinterpret_cast<const bf16x8*>(vb + 32 * S_), pfrag, acc_o[2], 0, 0, 0);
    acc_o[3] = __builtin_amdgcn_mfma_f32_16x16x32_bf16(
        *reinterpret_cast<const bf16x8*>(vb + 48 * S_), pfrag, acc_o[3], 0, 0, 0);
  }

  sm += __shfl_xor(sm, 16, 64);
  sm += __shfl_xor(sm, 32, 64);
  float il = 1.f / sm;

  #pragma unroll
  for (int n4 = 0; n4 < 4; ++n4) {
    u16x4 o;
    o.x = f2bf(acc_o[n4][0] * il);
    o.y = f2bf(acc_o[n4][1] * il);
    o.z = f2bf(acc_o[n4][2] * il);
    o.w = f2bf(acc_o[n4][3] * il);
    *reinterpret_cast<u16x4*>(ctx + (size_t)(b * S_ + qglob) * E_ + h * 64 + n4 * 16 + lk * 4) = o;
  }
}

extern "C" void kernel_launch(void* const* d_in, const int* in_sizes, int n_in,
                              void* d_out, int out_size, void* d_ws, size_t ws_size,
                              hipStream_t stream) {
  const float* val_emb = (const float*)d_in[0];
  const float* ring_emb = (const float*)d_in[1];
  const float* dist_emb = (const float*)d_in[2];
  const float* Wqkv = (const float*)d_in[3];
  const float* bqkv = (const float*)d_in[4];
  const float* Wo = (const float*)d_in[5];
  const float* bo = (const float*)d_in[6];
  const float* ln1_s = (const float*)d_in[7];
  const float* ln1_b = (const float*)d_in[8];
  const float* W1 = (const float*)d_in[9];
  const float* b1 = (const float*)d_in[10];
  const float* W2 = (const float*)d_in[11];
  const float* b2 = (const float*)d_in[12];
  const float* ln2_s = (const float*)d_in[13];
  const float* ln2_b = (const float*)d_in[14];
  const float* lnf_s = (const float*)d_in[15];
  const float* lnf_b = (const float*)d_in[16];
  const float* gen_W = (const float*)d_in[17];
  const float* gen_b = (const float*)d_in[18];
  const int* vseq = (const int*)d_in[19];
  const int* rseq = (const int*)d_in[20];
  const int* dist = (const int*)d_in[21];

  char* ws = (char*)d_ws;
  size_t off = 0;
  auto alloc = [&](size_t nbytes) {
    char* p = ws + off;
    off += (nbytes + 255) & ~(size_t)255;
    return p;
  };
  u16* gw_bf = (u16*)alloc((size_t)GEN_PAD * E_ * 2);
  u16* wqkv_l = (u16*)alloc((size_t)3 * E_ * E_ * 2);
  u16* wo_l = (u16*)alloc((size_t)E_ * E_ * 2);
  u16* w1_l = (u16*)alloc((size_t)F_ * E_ * 2);
  u16* w2_l = (u16*)alloc((size_t)E_ * F_ * 2);
  float* h = (float*)alloc((size_t)T_ * E_ * 4);
  u16* x_bf = (u16*)alloc((size_t)T_ * E_ * 2);
  u16* qkv_bf = (u16*)alloc((size_t)T_ * 3 * E_ * 2);
  u16* ctx_bf = (u16*)alloc((size_t)T_ * E_ * 2);
  u16* vt_bf = (u16*)alloc((size_t)B_ * H_ * 64 * S_ * 2);
  unsigned char* d8g = (unsigned char*)alloc((size_t)B_ * S_ * S_);
  u16* p_bf = (u16*)alloc((size_t)B_ * H_ * S_ * S_ * 2);
  u16* ff_bf = p_bf;
  float* psum = (float*)(p_bf + (size_t)T_ * F_);
  (void)ws_size; (void)in_sizes; (void)n_in; (void)out_size; (void)rseq;

  cvt_bf16<<<dim3((GEN_N * E_ / 4 + 255) / 256), dim3(256), 0, stream>>>(gen_W, gw_bf,
                                                                         GEN_N * E_);
  d8pre_k<<<dim3(B_ * S_ * S_ / 4 / 256), dim3(256), 0, stream>>>(dist, vseq, d8g);
  embed_k<<<dim3(T_), dim3(256), 0, stream>>>(val_emb, ring_emb, vseq, rseq, h, x_bf);

  for (int l = 0; l < L_; ++l) {
    cvt4_k<<<dim3(12288), dim3(256), 0, stream>>>(
        Wqkv + (size_t)l * 3 * E_ * E_, Wo + (size_t)l * E_ * E_,
        W1 + (size_t)l * F_ * E_, W2 + (size_t)l * E_ * F_,
        wqkv_l, wo_l, w1_l, w2_l);

    gemm_small<0><<<dim3(384), dim3(256), 0, stream>>>(
        x_bf, wqkv_l, bqkv + (size_t)l * 3 * E_, qkv_bf, vt_bf, T_, 3 * E_, E_, 12);
    attn_fused_k<<<dim3(B_ * H_ * 8), dim3(256), 0, stream>>>(qkv_bf, d8g, dist_emb,
                                                              vt_bf, ctx_bf);
    gemm_big<2, 2, 2><<<dim3(256), dim3(512), 0, stream>>>(
        ctx_bf, wo_l, nullptr, psum, T_, E_, E_, 8);
    ln_k<<<dim3(T_ / 4), dim3(256), 0, stream>>>(h, psum, psum + (size_t)T_ * E_,
                                                 bo + (size_t)l * E_,
                                                 ln1_s + (size_t)l * E_, ln1_b + (size_t)l * E_,
                                                 h, x_bf);
    gemm_small<1><<<dim3(512), dim3(256), 0, stream>>>(
        x_bf, w1_l, b1 + (size_t)l * F_, ff_bf, nullptr, T_, F_, E_, 16);
    gemm_big<2, 2, 2><<<dim3(256), dim3(512), 0, stream>>>(
        ff_bf, w2_l, nullptr, psum, T_, E_, F_, 8);
    ln_k<<<dim3(T_ / 4), dim3(256), 0, stream>>>(h, psum, psum + (size_t)T_ * E_,
                                                 b2 + (size_t)l * E_,
                                                 ln2_s + (size_t)l * E_, ln2_b + (size_t)l * E_,
                                                 h, x_bf);
  }
  ln_k<<<dim3(T_ / 4), dim3(256), 0, stream>>>(h, nullptr, nullptr, nullptr, lnf_s, lnf_b,
                                               nullptr, x_bf);
  gemm_big<3, 2, 1><<<dim3(160), dim3(512), 0, stream>>>(
      x_bf, gw_bf, gen_b, (float*)d_out, T_, GEN_N, E_, 10);
}

// Round 17
// 1021.041 us; speedup vs baseline: 1.0393x; 1.0393x over previous
//
#include <hip/hip_runtime.h>
#include <hip/hip_bf16.h>

typedef __attribute__((ext_vector_type(8))) short bf16x8;
typedef __attribute__((ext_vector_type(4))) float f32x4;
typedef unsigned short u16;
typedef __attribute__((ext_vector_type(4))) unsigned short u16x4;

#define L_ 4
#define E_ 1024
#define H_ 16
#define F_ 4096
#define B_ 8
#define S_ 512
#define T_ 4096
#define GEN_N 1200
#define GEN_PAD 1280
#define D8S 528   // d8 LDS row stride: 16B-aligned, 2-way-bank-free

#define AS1 __attribute__((address_space(1)))
#define AS3 __attribute__((address_space(3)))

static __device__ __forceinline__ u16 f2bf(float f) {
  unsigned u = __float_as_uint(f);
  unsigned r = (u + 0x7fffu + ((u >> 16) & 1u)) >> 16;
  return (u16)r;
}

static __device__ __forceinline__ unsigned cvt_pk_bf16(float lo, float hi) {
  unsigned r;
  asm("v_cvt_pk_bf16_f32 %0, %1, %2" : "=v"(r) : "v"(lo), "v"(hi));
  return r;
}

static __device__ __forceinline__ float fast_gelu(float v) {
  float y = 0.7978845608f * (v + 0.044715f * v * v * v);
  y = fminf(fmaxf(y, -9.f), 9.f);
  float e2 = __expf(2.f * y);
  float th = (e2 - 1.f) / (e2 + 1.f);
  return 0.5f * v * (1.f + th);
}

// ---------------- f32 -> bf16 convert (single buffer) ----------------
__global__ __launch_bounds__(256) void cvt_bf16(const float* __restrict__ src,
                                                u16* __restrict__ dst, int n) {
  int i = (blockIdx.x * 256 + threadIdx.x) * 4;
  if (i >= n) return;
  float4 v = *reinterpret_cast<const float4*>(src + i);
  u16x4 o = {f2bf(v.x), f2bf(v.y), f2bf(v.z), f2bf(v.w)};
  *reinterpret_cast<u16x4*>(dst + i) = o;
}

// ---------------- merged per-layer weight convert (4 segments) ----------------
__global__ __launch_bounds__(256) void cvt4_k(const float* __restrict__ s0,
                                              const float* __restrict__ s1,
                                              const float* __restrict__ s2,
                                              const float* __restrict__ s3,
                                              u16* __restrict__ d0, u16* __restrict__ d1,
                                              u16* __restrict__ d2, u16* __restrict__ d3) {
  int q = blockIdx.x * 256 + threadIdx.x;
  const float* s;
  u16* d;
  int i;
  if (q < 786432) { s = s0; d = d0; i = q; }
  else if (q < 786432 + 262144) { s = s1; d = d1; i = q - 786432; }
  else if (q < 786432 + 262144 + 1048576) { s = s2; d = d2; i = q - (786432 + 262144); }
  else { s = s3; d = d3; i = q - (786432 + 262144 + 1048576); }
  i *= 4;
  float4 v = *reinterpret_cast<const float4*>(s + i);
  u16x4 o = {f2bf(v.x), f2bf(v.y), f2bf(v.z), f2bf(v.w)};
  *reinterpret_cast<u16x4*>(d + i) = o;
}

// ---------------- dist -> u8 with pad sentinel (once per call) ----------------
__global__ __launch_bounds__(256) void d8pre_k(const int* __restrict__ dist,
                                               const int* __restrict__ vseq,
                                               unsigned char* __restrict__ d8g) {
  int idx = blockIdx.x * 256 + threadIdx.x;   // quad index over B*S*S/4
  int k4 = idx & 127;
  int b = idx >> 16;
  int4 dv = *reinterpret_cast<const int4*>(dist + (size_t)idx * 4);
  int4 vv = *reinterpret_cast<const int4*>(vseq + b * S_ + k4 * 4);
  uchar4 o;
  o.x = (vv.x == 0) ? (unsigned char)200 : (unsigned char)dv.x;
  o.y = (vv.y == 0) ? (unsigned char)200 : (unsigned char)dv.y;
  o.z = (vv.z == 0) ? (unsigned char)200 : (unsigned char)dv.z;
  o.w = (vv.w == 0) ? (unsigned char)200 : (unsigned char)dv.w;
  *reinterpret_cast<uchar4*>(d8g + (size_t)idx * 4) = o;
}

// ---------------- embedding ----------------
__global__ __launch_bounds__(256) void embed_k(const float* __restrict__ val_emb,
                                               const float* __restrict__ ring_emb,
                                               const int* __restrict__ vseq,
                                               const int* __restrict__ rseq,
                                               float* __restrict__ h, u16* __restrict__ xbf) {
  int tok = blockIdx.x;
  int e = threadIdx.x * 4;
  int v = vseq[tok], r = rseq[tok];
  float4 a = *reinterpret_cast<const float4*>(val_emb + v * E_ + e);
  float4 b = *reinterpret_cast<const float4*>(ring_emb + r * E_ + e);
  float4 o;
  o.x = (a.x + b.x) * 32.f; o.y = (a.y + b.y) * 32.f;
  o.z = (a.z + b.z) * 32.f; o.w = (a.w + b.w) * 32.f;
  *reinterpret_cast<float4*>(h + (size_t)tok * E_ + e) = o;
  u16x4 ob = {f2bf(o.x), f2bf(o.y), f2bf(o.z), f2bf(o.w)};
  *reinterpret_cast<u16x4*>(xbf + (size_t)tok * E_ + e) = ob;
}

// ---------------- LayerNorm: wave-per-token, 4 tokens/block -----------------
__global__ __launch_bounds__(256) void ln_k(const float* hin, const float* add0,
                                            const float* add1, const float* cbias,
                                            const float* g, const float* bta,
                                            float* hout, u16* xout) {
  int tok = blockIdx.x * 4 + (threadIdx.x >> 6);
  int lane = threadIdx.x & 63;
  const float* hp = hin + (size_t)tok * E_;
  float4 v[4];
  #pragma unroll
  for (int p = 0; p < 4; ++p) {
    int e = p * 256 + lane * 4;
    v[p] = *reinterpret_cast<const float4*>(hp + e);
    if (add0) {
      float4 a0 = *reinterpret_cast<const float4*>(add0 + (size_t)tok * E_ + e);
      float4 a1 = *reinterpret_cast<const float4*>(add1 + (size_t)tok * E_ + e);
      float4 cb = *reinterpret_cast<const float4*>(cbias + e);
      v[p].x += a0.x + a1.x + cb.x; v[p].y += a0.y + a1.y + cb.y;
      v[p].z += a0.z + a1.z + cb.z; v[p].w += a0.w + a1.w + cb.w;
    }
  }
  float s = 0.f, q = 0.f;
  #pragma unroll
  for (int p = 0; p < 4; ++p) {
    s += v[p].x + v[p].y + v[p].z + v[p].w;
    q += v[p].x * v[p].x + v[p].y * v[p].y + v[p].z * v[p].z + v[p].w * v[p].w;
  }
  #pragma unroll
  for (int off = 1; off < 64; off <<= 1) {
    s += __shfl_xor(s, off, 64);
    q += __shfl_xor(q, off, 64);
  }
  float mean = s * (1.f / E_);
  float var = q * (1.f / E_) - mean * mean;
  float inv = rsqrtf(var + 1e-5f);
  #pragma unroll
  for (int p = 0; p < 4; ++p) {
    int e = p * 256 + lane * 4;
    float4 gg = *reinterpret_cast<const float4*>(g + e);
    float4 bb = *reinterpret_cast<const float4*>(bta + e);
    float4 o;
    o.x = (v[p].x - mean) * inv * gg.x + bb.x;
    o.y = (v[p].y - mean) * inv * gg.y + bb.y;
    o.z = (v[p].z - mean) * inv * gg.z + bb.z;
    o.w = (v[p].w - mean) * inv * gg.w + bb.w;
    if (hout) *reinterpret_cast<float4*>(hout + (size_t)tok * E_ + e) = o;
    u16x4 ob = {f2bf(o.x), f2bf(o.y), f2bf(o.z), f2bf(o.w)};
    *reinterpret_cast<u16x4*>(xout + (size_t)tok * E_ + e) = ob;
  }
}

// ---------------- gemm_small: 128x256 tile, BK=32, 48KB LDS, 2 blocks/CU -------
// EPI: 0 = bf16+bias (+Vt scatter), 1 = gelu bf16+bias
template <int EPI>
__global__ __launch_bounds__(256, 2) void gemm_small(const u16* __restrict__ A,
                                                     const u16* __restrict__ W,
                                                     const float* __restrict__ bias,
                                                     void* __restrict__ Cp,
                                                     u16* __restrict__ Vt,
                                                     int M, int N, int K, int tilesN) {
  __shared__ __align__(16) char lds[49152];
  int tid = threadIdx.x;
  int wid = tid >> 6, l = tid & 63;
  int wm = wid >> 1, wn = wid & 1;
  int lr = l & 15, lk = l >> 4;
  int nwg = gridDim.x, bid = blockIdx.x;
  int swz = ((nwg & 7) == 0) ? ((bid & 7) * (nwg >> 3) + (bid >> 3)) : bid;
  int tm = swz / tilesN, tn = swz % tilesN;
  int row0 = tm * 128, col0 = tn * 256;

  int srow = tid >> 2;
  int sch = ((tid & 3) ^ ((srow >> 1) & 3)) * 8;
  const u16* gA = A + (size_t)(row0 + srow) * K + sch;
  const u16* gB = W + (size_t)(col0 + srow) * K + sch;
  int wslot = wid * 1024;

  auto stage = [&](int buf, int kt) {
    size_t ko = (size_t)kt * 32;
    int base = buf * 24576;
    #pragma unroll
    for (int i = 0; i < 2; ++i)
      __builtin_amdgcn_global_load_lds((const AS1 void*)(gA + (size_t)i * 64 * K + ko),
                                       (AS3 void*)(lds + base + i * 4096 + wslot), 16, 0, 0);
    #pragma unroll
    for (int i = 0; i < 4; ++i)
      __builtin_amdgcn_global_load_lds((const AS1 void*)(gB + (size_t)i * 64 * K + ko),
                                       (AS3 void*)(lds + base + 8192 + i * 4096 + wslot), 16, 0, 0);
  };

  int ck = (lk ^ ((lr >> 1) & 3)) * 16;
  f32x4 acc[4][8];
  f32x4 z = {0.f, 0.f, 0.f, 0.f};
  #pragma unroll
  for (int m = 0; m < 4; ++m)
    #pragma unroll
    for (int n = 0; n < 8; ++n) acc[m][n] = z;

  auto compute = [&](int buf) {
    int base = buf * 24576;
    bf16x8 bfr[8];
    #pragma unroll
    for (int n = 0; n < 8; ++n)
      bfr[n] = *reinterpret_cast<const bf16x8*>(lds + base + 8192 + (wn * 128 + n * 16 + lr) * 64 + ck);
    #pragma unroll
    for (int m = 0; m < 4; ++m) {
      bf16x8 af = *reinterpret_cast<const bf16x8*>(lds + base + (wm * 64 + m * 16 + lr) * 64 + ck);
      #pragma unroll
      for (int n = 0; n < 8; ++n)
        acc[m][n] = __builtin_amdgcn_mfma_f32_16x16x32_bf16(af, bfr[n], acc[m][n], 0, 0, 0);
    }
  };

  int nt = K >> 5;
  stage(0, 0);
  int cur = 0;
  for (int t = 0; t < nt; ++t) {
    if (t + 1 < nt) {
      stage(cur ^ 1, t + 1);
      asm volatile("s_waitcnt vmcnt(6)" ::: "memory");
    } else {
      asm volatile("s_waitcnt vmcnt(0)" ::: "memory");
    }
    __builtin_amdgcn_s_barrier();
    asm volatile("" ::: "memory");
    compute(cur);
    asm volatile("" ::: "memory");
    __builtin_amdgcn_s_barrier();
    cur ^= 1;
  }

  #pragma unroll
  for (int n = 0; n < 8; ++n) {
    int col = col0 + wn * 128 + n * 16 + lr;
    float bv = bias[col];
    #pragma unroll
    for (int m = 0; m < 4; ++m) {
      int rbase = row0 + wm * 64 + m * 16 + lk * 4;
      #pragma unroll
      for (int r2 = 0; r2 < 4; ++r2) {
        float v = acc[m][n][r2] + bv;
        if (EPI == 1) v = fast_gelu(v);
        int row = rbase + r2;
        u16 bw = f2bf(v);
        ((u16*)Cp)[(size_t)row * N + col] = bw;
        if (EPI == 0 && Vt != nullptr && col >= 2 * E_) {
          int dg = col - 2 * E_;
          int hh = dg >> 6, dd = dg & 63;
          int bb = row >> 9, ss = row & 511;
          Vt[((size_t)((bb * 16 + hh) * 64 + dd) << 9) + ss] = bw;
        }
      }
    }
  }
}

// ---------------- big-tile GEMM (2-phase, Wo / W2 / gen) ----------------
// EPI: 2 = raw f32 partial (split-K), 3 = f32+bias
template <int EPI, int NW, int SPLITK>
__global__ __launch_bounds__(512, 2) void gemm_big(const u16* __restrict__ A,
                                                   const u16* __restrict__ W,
                                                   const float* __restrict__ bias,
                                                   void* __restrict__ Cp,
                                                   int M, int N, int K, int tilesN) {
  constexpr int BN = 64 * NW;
  __shared__ __align__(16) u16 As[2][256 * 64];
  __shared__ __align__(16) u16 Bs[2][BN * 64];
  int tid = threadIdx.x;
  int wid = tid >> 6, ln = tid & 63;
  int wm = wid >> 2, wn = wid & 3;
  int lr = ln & 15, lk = ln >> 4;
  int nwg = gridDim.x;
  int bid = blockIdx.x;
  int swz = ((nwg & 7) == 0) ? ((bid & 7) * (nwg >> 3) + (bid >> 3)) : bid;
  int sp = 0, tile = swz;
  if (SPLITK > 1) { sp = swz & (SPLITK - 1); tile = swz / SPLITK; }
  int tm = tile / tilesN, tn = tile % tilesN;
  int row0 = tm * 256, col0 = tn * BN;
  int Ks = K / SPLITK;
  int kbase = sp * Ks;

  int srow = tid >> 3;
  int schunk = ((tid & 7) ^ (srow & 7)) * 8;
  const u16* gA = A + (size_t)(row0 + srow) * K + kbase + schunk;
  const u16* gB = W + (size_t)(col0 + srow) * K + kbase + schunk;
  size_t ldsBase = (size_t)((wid << 3) * 64) * 2;

  auto stage = [&](int buf, int kt) {
    size_t ko = (size_t)kt * 64;
    #pragma unroll
    for (int i = 0; i < 4; ++i)
      __builtin_amdgcn_global_load_lds(
          (const AS1 void*)(gA + (size_t)i * 64 * K + ko),
          (AS3 void*)((char*)&As[buf][0] + ldsBase + (size_t)i * 64 * 128), 16, 0, 0);
    #pragma unroll
    for (int i = 0; i < NW; ++i)
      __builtin_amdgcn_global_load_lds(
          (const AS1 void*)(gB + (size_t)i * 64 * K + ko),
          (AS3 void*)((char*)&Bs[buf][0] + ldsBase + (size_t)i * 64 * 128), 16, 0, 0);
  };

  f32x4 acc[8][NW];
  f32x4 z = {0.f, 0.f, 0.f, 0.f};
  #pragma unroll
  for (int m = 0; m < 8; ++m)
    #pragma unroll
    for (int n = 0; n < NW; ++n) acc[m][n] = z;

  auto compute = [&](int buf) {
    #pragma unroll
    for (int s = 0; s < 2; ++s) {
      int ch = ((s * 4 + lk) ^ (lr & 7)) * 8;
      bf16x8 bfr[NW];
      #pragma unroll
      for (int n = 0; n < NW; ++n)
        bfr[n] = *reinterpret_cast<const bf16x8*>(&Bs[buf][(wn * (16 * NW) + n * 16 + lr) * 64 + ch]);
      #pragma unroll
      for (int m = 0; m < 8; ++m) {
        bf16x8 af = *reinterpret_cast<const bf16x8*>(&As[buf][(wm * 128 + m * 16 + lr) * 64 + ch]);
        #pragma unroll
        for (int n = 0; n < NW; ++n)
          acc[m][n] = __builtin_amdgcn_mfma_f32_16x16x32_bf16(af, bfr[n], acc[m][n], 0, 0, 0);
      }
    }
  };

  int nt = Ks >> 6;
  stage(0, 0);
  int cur = 0;
  for (int t = 0; t < nt; ++t) {
    if (t + 1 < nt) {
      stage(cur ^ 1, t + 1);
      if constexpr (NW == 2) asm volatile("s_waitcnt vmcnt(6)" ::: "memory");
      else if constexpr (NW == 3) asm volatile("s_waitcnt vmcnt(7)" ::: "memory");
      else asm volatile("s_waitcnt vmcnt(8)" ::: "memory");
    } else {
      asm volatile("s_waitcnt vmcnt(0)" ::: "memory");
    }
    __builtin_amdgcn_s_barrier();
    asm volatile("" ::: "memory");
    compute(cur);
    asm volatile("" ::: "memory");
    __builtin_amdgcn_s_barrier();
    cur ^= 1;
  }

  #pragma unroll
  for (int n = 0; n < NW; ++n) {
    int col = col0 + wn * (16 * NW) + n * 16 + lr;
    if (col >= N) continue;
    float bv = (EPI == 2) ? 0.f : bias[col];
    #pragma unroll
    for (int m = 0; m < 8; ++m) {
      int rbase = row0 + wm * 128 + m * 16 + lk * 4;
      #pragma unroll
      for (int r2 = 0; r2 < 4; ++r2) {
        float v = acc[m][n][r2] + bv;
        int row = rbase + r2;
        if (EPI == 2)
          ((float*)Cp)[(size_t)sp * M * N + (size_t)row * N + col] = v;
        else
          ((float*)Cp)[(size_t)row * N + col] = v;
      }
    }
  }
}

// ---------------- fused attention (R14 structure; d8 staged from d8g) ----------
__global__ __launch_bounds__(256, 4) void attn_fused_k(const u16* __restrict__ qkv,
                                                       const unsigned char* __restrict__ d8g,
                                                       const float* __restrict__ dist_emb,
                                                       const u16* __restrict__ Vt,
                                                       u16* __restrict__ ctx) {
  int blk = blockIdx.x;
  int bh = blk & 127;
  int qt = blk >> 7;
  int b = bh >> 4, h = bh & 15;
  int tid = threadIdx.x, wv = tid >> 6, l = tid & 63;
  int lr = l & 15, lk = l >> 4;

  __shared__ float de[208];
  __shared__ __align__(16) unsigned char d8[64 * D8S];

  int ncol = (qt + 1) * 64;
  for (int i = tid; i < 208; i += 256)
    de[i] = (i < 200) ? dist_emb[i * H_ + h] : -1e30f;
  {
    // copy 64 rows x ncol bytes of precomputed u8 dist (contiguous per row)
    int r = tid >> 2;
    const unsigned char* srow = d8g + ((size_t)(b * S_ + qt * 64 + r) << 9);
    int nc16 = ncol >> 4;
    for (int c = (tid & 3); c < nc16; c += 4) {
      int4 v = *reinterpret_cast<const int4*>(srow + c * 16);
      *reinterpret_cast<int4*>(&d8[r * D8S + c * 16]) = v;
    }
  }
  __syncthreads();

  int q0 = qt * 64 + wv * 16;
  int nv = 4 * qt + wv + 1;
  int qglob = q0 + lr;
  int qloc = wv * 16 + lr;

  bf16x8 aq0 = *reinterpret_cast<const bf16x8*>(
      qkv + (size_t)(b * S_ + q0 + lr) * 3072 + h * 64 + lk * 8);
  bf16x8 aq1 = *reinterpret_cast<const bf16x8*>(
      qkv + (size_t)(b * S_ + q0 + lr) * 3072 + h * 64 + 32 + lk * 8);

  float sm = 0.f;
  f32x4 z = {0.f, 0.f, 0.f, 0.f};
  f32x4 acc_o[4] = {z, z, z, z};

  int sA = lr + ((2 * lk) & 3) * 16;
  int sB = lr + ((2 * lk + 1) & 3) * 16;
  int jsel = (lk >= 2);

  const u16* kBase = qkv + (size_t)(b * S_ + lr) * 3072 + E_ + h * 64 + lk * 8;
  const u16* vBase = Vt + (size_t)(bh * 64 + lr) * S_ + lk * 8;

  int ngroups = (nv + 1) >> 1;
  #pragma unroll 1
  for (int g = 0; g < ngroups; ++g) {
    // ---- QK^T (swapped) ----
    f32x4 s0 = z, s1 = z;
    {
      const u16* kb = kBase + (size_t)(2 * g) * 16 * 3072;
      bf16x8 bk0 = *reinterpret_cast<const bf16x8*>(kb);
      bf16x8 bk1 = *reinterpret_cast<const bf16x8*>(kb + 32);
      s0 = __builtin_amdgcn_mfma_f32_16x16x32_bf16(bk0, aq0, s0, 0, 0, 0);
      s0 = __builtin_amdgcn_mfma_f32_16x16x32_bf16(bk1, aq1, s0, 0, 0, 0);
    }
    if (2 * g + 1 < nv) {
      const u16* kb = kBase + (size_t)(2 * g + 1) * 16 * 3072;
      bf16x8 bk0 = *reinterpret_cast<const bf16x8*>(kb);
      bf16x8 bk1 = *reinterpret_cast<const bf16x8*>(kb + 32);
      s1 = __builtin_amdgcn_mfma_f32_16x16x32_bf16(bk0, aq0, s1, 0, 0, 0);
      s1 = __builtin_amdgcn_mfma_f32_16x16x32_bf16(bk1, aq1, s1, 0, 0, 0);
    }
    // ---- bias + causal + exp (u32 LDS gather of d8) ----
    float e0[4], e1[4];
    {
      unsigned dd = *reinterpret_cast<const unsigned*>(&d8[qloc * D8S + (2 * g) * 16 + lk * 4]);
      #pragma unroll
      for (int r2 = 0; r2 < 4; ++r2) {
        int kg = (2 * g) * 16 + lk * 4 + r2;
        float e = 0.f;
        if (kg <= qglob)
          e = __expf(s0[r2] * 0.125f + de[(dd >> (8 * r2)) & 255]);
        e0[r2] = e; sm += e;
      }
    }
    {
      unsigned dd = *reinterpret_cast<const unsigned*>(&d8[qloc * D8S + (2 * g + 1) * 16 + lk * 4]);
      #pragma unroll
      for (int r2 = 0; r2 < 4; ++r2) {
        int kg = (2 * g + 1) * 16 + lk * 4 + r2;
        float e = 0.f;
        if (2 * g + 1 < nv && kg <= qglob)
          e = __expf(s1[r2] * 0.125f + de[(dd >> (8 * r2)) & 255]);
        e1[r2] = e; sm += e;
      }
    }
    // ---- pack + shuffle into PV B-frag ----
    unsigned t0p0 = cvt_pk_bf16(e0[0], e0[1]);
    unsigned t0p1 = cvt_pk_bf16(e0[2], e0[3]);
    unsigned t1p0 = cvt_pk_bf16(e1[0], e1[1]);
    unsigned t1p1 = cvt_pk_bf16(e1[2], e1[3]);
    unsigned a00 = __shfl((int)t0p0, sA, 64), a10 = __shfl((int)t1p0, sA, 64);
    unsigned a01 = __shfl((int)t0p1, sA, 64), a11 = __shfl((int)t1p1, sA, 64);
    unsigned b00 = __shfl((int)t0p0, sB, 64), b10 = __shfl((int)t1p0, sB, 64);
    unsigned b01 = __shfl((int)t0p1, sB, 64), b11 = __shfl((int)t1p1, sB, 64);
    unsigned w0 = jsel ? a10 : a00;
    unsigned w1 = jsel ? a11 : a01;
    unsigned w2 = jsel ? b10 : b00;
    unsigned w3 = jsel ? b11 : b01;
    bf16x8 pfrag;
    {
      unsigned pw[4] = {w0, w1, w2, w3};
      pfrag = *reinterpret_cast<bf16x8*>(pw);
    }
    // ---- PV ----
    const u16* vb = vBase + g * 32;
    acc_o[0] = __builtin_amdgcn_mfma_f32_16x16x32_bf16(
        *reinterpret_cast<const bf16x8*>(vb), pfrag, acc_o[0], 0, 0, 0);
    acc_o[1] = __builtin_amdgcn_mfma_f32_16x16x32_bf16(
        *reinterpret_cast<const bf16x8*>(vb + 16 * S_), pfrag, acc_o[1], 0, 0, 0);
    acc_o[2] = __builtin_amdgcn_mfma_f32_16x16x32_bf16(
        *reinterpret_cast<const bf16x8*>(vb + 32 * S_), pfrag, acc_o[2], 0, 0, 0);
    acc_o[3] = __builtin_amdgcn_mfma_f32_16x16x32_bf16(
        *reinterpret_cast<const bf16x8*>(vb + 48 * S_), pfrag, acc_o[3], 0, 0, 0);
  }

  sm += __shfl_xor(sm, 16, 64);
  sm += __shfl_xor(sm, 32, 64);
  float il = 1.f / sm;

  #pragma unroll
  for (int n4 = 0; n4 < 4; ++n4) {
    u16x4 o;
    o.x = f2bf(acc_o[n4][0] * il);
    o.y = f2bf(acc_o[n4][1] * il);
    o.z = f2bf(acc_o[n4][2] * il);
    o.w = f2bf(acc_o[n4][3] * il);
    *reinterpret_cast<u16x4*>(ctx + (size_t)(b * S_ + qglob) * E_ + h * 64 + n4 * 16 + lk * 4) = o;
  }
}

extern "C" void kernel_launch(void* const* d_in, const int* in_sizes, int n_in,
                              void* d_out, int out_size, void* d_ws, size_t ws_size,
                              hipStream_t stream) {
  const float* val_emb = (const float*)d_in[0];
  const float* ring_emb = (const float*)d_in[1];
  const float* dist_emb = (const float*)d_in[2];
  const float* Wqkv = (const float*)d_in[3];
  const float* bqkv = (const float*)d_in[4];
  const float* Wo = (const float*)d_in[5];
  const float* bo = (const float*)d_in[6];
  const float* ln1_s = (const float*)d_in[7];
  const float* ln1_b = (const float*)d_in[8];
  const float* W1 = (const float*)d_in[9];
  const float* b1 = (const float*)d_in[10];
  const float* W2 = (const float*)d_in[11];
  const float* b2 = (const float*)d_in[12];
  const float* ln2_s = (const float*)d_in[13];
  const float* ln2_b = (const float*)d_in[14];
  const float* lnf_s = (const float*)d_in[15];
  const float* lnf_b = (const float*)d_in[16];
  const float* gen_W = (const float*)d_in[17];
  const float* gen_b = (const float*)d_in[18];
  const int* vseq = (const int*)d_in[19];
  const int* rseq = (const int*)d_in[20];
  const int* dist = (const int*)d_in[21];

  char* ws = (char*)d_ws;
  size_t off = 0;
  auto alloc = [&](size_t nbytes) {
    char* p = ws + off;
    off += (nbytes + 255) & ~(size_t)255;
    return p;
  };
  u16* gw_bf = (u16*)alloc((size_t)GEN_PAD * E_ * 2);
  u16* wqkv_l = (u16*)alloc((size_t)3 * E_ * E_ * 2);
  u16* wo_l = (u16*)alloc((size_t)E_ * E_ * 2);
  u16* w1_l = (u16*)alloc((size_t)F_ * E_ * 2);
  u16* w2_l = (u16*)alloc((size_t)E_ * F_ * 2);
  float* h = (float*)alloc((size_t)T_ * E_ * 4);
  u16* x_bf = (u16*)alloc((size_t)T_ * E_ * 2);
  u16* qkv_bf = (u16*)alloc((size_t)T_ * 3 * E_ * 2);
  u16* ctx_bf = (u16*)alloc((size_t)T_ * E_ * 2);
  u16* vt_bf = (u16*)alloc((size_t)B_ * H_ * 64 * S_ * 2);
  unsigned char* d8g = (unsigned char*)alloc((size_t)B_ * S_ * S_);
  u16* p_bf = (u16*)alloc((size_t)B_ * H_ * S_ * S_ * 2);
  u16* ff_bf = p_bf;
  float* psum = (float*)(p_bf + (size_t)T_ * F_);
  (void)ws_size; (void)in_sizes; (void)n_in; (void)out_size; (void)rseq;

  cvt_bf16<<<dim3((GEN_N * E_ / 4 + 255) / 256), dim3(256), 0, stream>>>(gen_W, gw_bf,
                                                                         GEN_N * E_);
  d8pre_k<<<dim3(B_ * S_ * S_ / 4 / 256), dim3(256), 0, stream>>>(dist, vseq, d8g);
  embed_k<<<dim3(T_), dim3(256), 0, stream>>>(val_emb, ring_emb, vseq, rseq, h, x_bf);

  for (int l = 0; l < L_; ++l) {
    cvt4_k<<<dim3(12288), dim3(256), 0, stream>>>(
        Wqkv + (size_t)l * 3 * E_ * E_, Wo + (size_t)l * E_ * E_,
        W1 + (size_t)l * F_ * E_, W2 + (size_t)l * E_ * F_,
        wqkv_l, wo_l, w1_l, w2_l);

    gemm_small<0><<<dim3(384), dim3(256), 0, stream>>>(
        x_bf, wqkv_l, bqkv + (size_t)l * 3 * E_, qkv_bf, vt_bf, T_, 3 * E_, E_, 12);
    attn_fused_k<<<dim3(B_ * H_ * 8), dim3(256), 0, stream>>>(qkv_bf, d8g, dist_emb,
                                                              vt_bf, ctx_bf);
    gemm_big<2, 2, 2><<<dim3(256), dim3(512), 0, stream>>>(
        ctx_bf, wo_l, nullptr, psum, T_, E_, E_, 8);
    ln_k<<<dim3(T_ / 4), dim3(256), 0, stream>>>(h, psum, psum + (size_t)T_ * E_,
                                                 bo + (size_t)l * E_,
                                                 ln1_s + (size_t)l * E_, ln1_b + (size_t)l * E_,
                                                 h, x_bf);
    gemm_small<1><<<dim3(512), dim3(256), 0, stream>>>(
        x_bf, w1_l, b1 + (size_t)l * F_, ff_bf, nullptr, T_, F_, E_, 16);
    gemm_big<2, 2, 2><<<dim3(256), dim3(512), 0, stream>>>(
        ff_bf, w2_l, nullptr, psum, T_, E_, F_, 8);
    ln_k<<<dim3(T_ / 4), dim3(256), 0, stream>>>(h, psum, psum + (size_t)T_ * E_,
                                                 b2 + (size_t)l * E_,
                                                 ln2_s + (size_t)l * E_, ln2_b + (size_t)l * E_,
                                                 h, x_bf);
  }
  ln_k<<<dim3(T_ / 4), dim3(256), 0, stream>>>(h, nullptr, nullptr, nullptr, lnf_s, lnf_b,
                                               nullptr, x_bf);
  gemm_big<3, 2, 1><<<dim3(160), dim3(512), 0, stream>>>(
      x_bf, gw_bf, gen_b, (float*)d_out, T_, GEN_N, E_, 10);
}